// Round 12
// baseline (138.650 us; speedup 1.0000x reference)
//
#include <hip/hip_runtime.h>

typedef unsigned int  uint;
typedef unsigned short ushort;

#define N_PTS  1048576
#define BLOCK  1024
#define WAVES  16
#define NPT    4
#define CHUNK  (WAVES * NPT * 16)     // 1024 points per block-iteration
#define NCHUNK (N_PTS / CHUNK)        // 1024, exact
#define GRID   256                    // 1 block/CU, 16 waves/CU, 4 iters/block

static_assert(N_PTS % CHUNK == 0, "chunking");
static_assert(NCHUNK % GRID == 0, "grid stride");

typedef __attribute__((ext_vector_type(8))) _Float16 f16x8;
typedef __attribute__((ext_vector_type(2))) _Float16 f16x2;
typedef __attribute__((ext_vector_type(4))) float    f32x4;

struct Params {
    const float* emb[3];
    const float* views;
    const float* mask[3];
    const float* w[21];
    float* out;
};

// Pre-arranged f16 A-fragment weight blob (k-permuted), written per launch.
__device__ uint g_wbuf[3 * 9216];

// per-branch weight blob layout (u16 offsets)
#define OFF_S0 0
#define OFF_S1 2048
#define OFF_S2 6144
#define OFF_C0 7168
#define OFF_C1 9216
#define OFF_C2 13312
#define OFF_C3 17408
#define BR_SZ  18432

// f32 pair -> packed f16x2, RNE (for weights; prep-time only)
__device__ __forceinline__ uint cvt2w(float a, float b) {
    f16x2 v = {(_Float16)a, (_Float16)b};
    return __builtin_bit_cast(uint, v);
}
// f32 pair -> packed f16x2 via v_cvt_pkrtz_f16_f32 (hot path)
__device__ __forceinline__ uint cvt2(float a, float b) {
    return __builtin_bit_cast(uint, __builtin_amdgcn_cvt_pkrtz(a, b));
}
// packed relu: v_pk_max_f16 with +0  (elementwise_max on <2 x half>)
__device__ __forceinline__ uint maxz(uint x) {
    f16x2 v = __builtin_bit_cast(f16x2, x);
    f16x2 z = {(_Float16)0.f, (_Float16)0.f};
    return __builtin_bit_cast(uint, __builtin_elementwise_max(v, z));
}

__device__ __forceinline__ f32x4 MFMA(f16x8 a, f16x8 b, f32x4 c) {
    return __builtin_amdgcn_mfma_f32_16x16x32_f16(a, b, c, 0, 0, 0);
}

__device__ __forceinline__ float fast_rcp(float x) { return __builtin_amdgcn_rcpf(x); }

// Weight value at PHYSICAL k-slot kp, output col m, with the k-permutation
// k̃ = 32*(mt>>1) + 8g + 4*(mt&1) + r  inverted:  f = 16*((e>>2)+2h) + 4g + (e&3).
// Layers: 0=S0(identity,32x64) 1=S1 2=S2(64x17,col-remap) 3=C0(K=32,geo+views)
//         4=C1 5=C2 6=C3(64x3)
__device__ __forceinline__ float wphys(int L, int br, const float* W, int kp, int m) {
    if (L == 0) return W[kp * 64 + m];                    // S0: inputs from global
    const int g = (kp & 31) >> 3, e = kp & 7, h = kp >> 5;
    if (L == 3) {                                         // C0: K=32 handoff16 + views
        if (e < 4) {
            const int f = 4 * g + e;                      // S2-output feature (0=sigma)
            if (f < 1) return 0.f;
            return (br == 0) ? W[(f + 2) * 64 + m] : W[(f - 1) * 64 + m];
        }
        return (br == 0 && g == 0 && e <= 6) ? W[(e - 4) * 64 + m] : 0.f;
    }
    const int f = 16 * ((e >> 2) + 2 * h) + 4 * g + (e & 3);
    if (L == 2) return W[f * 17 + (m == 0 ? 0 : m + 1)];  // S2: m0=sigma, m>=1=geo m-1
    if (L == 6) return (m < 3) ? W[f * 3 + m] : 0.f;      // C3: rgb
    return W[f * 64 + m];                                  // S1,C1,C2: 64x64
}

// ------------------- prologue: arrange weights as A-fragments -------------------
__global__ void prep_weights(Params P) {
    const int idx = blockIdx.x * 256 + threadIdx.x;   // 0 .. 27647
    const int br  = idx / 9216;
    const int rem = idx - br * 9216;
    int L, q;
    if      (rem < 1024) { L = 0; q = rem;        }
    else if (rem < 3072) { L = 1; q = rem - 1024; }
    else if (rem < 3584) { L = 2; q = rem - 3072; }
    else if (rem < 4608) { L = 3; q = rem - 3584; }
    else if (rem < 6656) { L = 4; q = rem - 4608; }
    else if (rem < 8704) { L = 5; q = rem - 6656; }
    else                 { L = 6; q = rem - 8704; }
    const float* W   = P.w[br * 7 + L];
    const int kk_n   = (L == 0 || L == 3) ? 1 : 2;
    const int E  = q * 2;            // u16 element index within layer blob (even)
    const int b  = E >> 9;           // 512-elem fragment block
    const int ln = (E >> 3) & 63;    // lane within block
    const int e  = E & 7;            // element within lane (even)
    const int mt = b / kk_n;
    const int kk = b - mt * kk_n;
    const int m  = mt * 16 + (ln & 15);
    const int kp = kk * 32 + (ln >> 4) * 8 + e;   // physical k-slot
    g_wbuf[idx] = cvt2w(wphys(L, br, W, kp, m), wphys(L, br, W, kp + 1, m));
}

// D-layout acc -> next layer's B fragments, PURE in-lane (weights k-permuted):
// feature 16mt+4g+r  ->  k̃ = 32*(mt>>1) + 8g + 4*(mt&1) + r   (same lane group g)
template<bool RELU>
__device__ __forceinline__ void handoff64(const f32x4 (&a)[4], uint4 &b0, uint4 &b1) {
#pragma unroll
    for (int h = 0; h < 2; ++h) {
        const f32x4 &lo = a[2 * h], &hi = a[2 * h + 1];
        uint w0 = cvt2(lo[0], lo[1]);
        uint w1 = cvt2(lo[2], lo[3]);
        uint w2 = cvt2(hi[0], hi[1]);
        uint w3 = cvt2(hi[2], hi[3]);
        if (RELU) { w0 = maxz(w0); w1 = maxz(w1); w2 = maxz(w2); w3 = maxz(w3); }
        uint4 &b = h ? b1 : b0;
        b.x = w0; b.y = w1; b.z = w2; b.w = w3;
    }
}

// hidden 64->64 layer with fused relu-handoff: weights from LDS (loaded once
// per layer, amortized over NPT tiles), activations register-resident.
__device__ __forceinline__ void layer64(const ushort* lw, int lane,
                                        uint4 (&b0)[NPT], uint4 (&b1)[NPT]) {
    f16x8 wf[8];
#pragma unroll
    for (int b = 0; b < 8; ++b) wf[b] = *(const f16x8*)(lw + b * 512 + lane * 8);
#pragma unroll
    for (int t = 0; t < NPT; ++t) {
        const f16x8 i0 = __builtin_bit_cast(f16x8, b0[t]);
        const f16x8 i1 = __builtin_bit_cast(f16x8, b1[t]);
        f32x4 acc[4];
#pragma unroll
        for (int mt = 0; mt < 4; ++mt) {
            f32x4 a = (f32x4){0.f, 0.f, 0.f, 0.f};
            a = MFMA(wf[mt * 2 + 0], i0, a);
            a = MFMA(wf[mt * 2 + 1], i1, a);
            acc[mt] = a;
        }
        handoff64<true>(acc, b0[t], b1[t]);   // immediate: short acc lifetime
    }
}

__global__ __launch_bounds__(BLOCK, 4) void nerf_main(Params P) {
    __shared__ __align__(16) ushort lds_w[3 * BR_SZ];   // 108 KB weights, no act LDS

    const int tid = threadIdx.x;
    // ---- stage pre-arranged weight blob global -> LDS, once per block ----
    {
        const uint4* src = (const uint4*)g_wbuf;     // 6912 uint4
        uint4* dst = (uint4*)lds_w;
        for (int i = tid; i < 6912; i += BLOCK) dst[i] = src[i];
    }
    __syncthreads();

    const int wave = tid >> 6;
    const int lane = tid & 63;
    const int c = lane & 15;   // point within tile
    const int g = lane >> 4;   // lane group

#pragma unroll 1
    for (int ch = blockIdx.x; ch < NCHUNK; ch += gridDim.x) {
        const int p0 = ch * CHUNK + wave * (NPT * 16);

        float stot[NPT], car[NPT], cag[NPT], cab[NPT];
#pragma unroll
        for (int t = 0; t < NPT; ++t) { stot[t] = 0.f; car[t] = 0.f; cag[t] = 0.f; cab[t] = 0.f; }

#pragma unroll 1
        for (int br = 0; br < 3; ++br) {
            const ushort* lw  = lds_w + br * BR_SZ;
            const float* emb  = P.emb[br];
            const float* msk  = P.mask[br];
            float sig_pre[NPT], rp[NPT], gp[NPT], bp[NPT];
            uint4 b0[NPT], b1[NPT];

            // ---- sigma L0 : emb(32) -> 64, relu (B built straight from global f32)
            {
                f16x8 wf[4];
#pragma unroll
                for (int b = 0; b < 4; ++b)
                    wf[b] = *(const f16x8*)(lw + OFF_S0 + b * 512 + lane * 8);
#pragma unroll
                for (int t = 0; t < NPT; ++t) {
                    const float* ep = emb + (size_t)(p0 + t * 16 + c) * 32 + g * 8;
                    const float4 ea = *(const float4*)ep;
                    const float4 eb = *(const float4*)(ep + 4);
                    uint4 iv;
                    iv.x = cvt2(ea.x, ea.y); iv.y = cvt2(ea.z, ea.w);
                    iv.z = cvt2(eb.x, eb.y); iv.w = cvt2(eb.z, eb.w);
                    const f16x8 inf = __builtin_bit_cast(f16x8, iv);
                    f32x4 acc[4];
#pragma unroll
                    for (int mt = 0; mt < 4; ++mt) {
                        f32x4 a = (f32x4){0.f, 0.f, 0.f, 0.f};
                        acc[mt] = MFMA(wf[mt], inf, a);
                    }
                    handoff64<true>(acc, b0[t], b1[t]);
                }
            }

            // ---- sigma L1 : 64 -> 64, relu
            layer64(lw + OFF_S1, lane, b0, b1);

            // ---- sigma L2 : 64 -> 16 [f0=sigma-pre, f1..15=geo], raw ----
            {
                const f16x8 w0 = *(const f16x8*)(lw + OFF_S2 + 0 * 512 + lane * 8);
                const f16x8 w1 = *(const f16x8*)(lw + OFF_S2 + 1 * 512 + lane * 8);
#pragma unroll
                for (int t = 0; t < NPT; ++t) {
                    f32x4 a = (f32x4){0.f, 0.f, 0.f, 0.f};
                    a = MFMA(w0, __builtin_bit_cast(f16x8, b0[t]), a);
                    a = MFMA(w1, __builtin_bit_cast(f16x8, b1[t]), a);
                    sig_pre[t] = a[0];   // feature 0, valid at g==0 (lanes 0..15)
                    // in-lane handoff16 -> C0 B-fragment (features 4g+r at e=0..3)
                    uint4 nb;
                    nb.x = cvt2(a[0], a[1]);
                    nb.y = cvt2(a[2], a[3]);
                    nb.z = 0u; nb.w = 0u;
                    if (br == 0 && g == 0) {   // views at k̃=4,5,6 (g==0, e=4..6)
                        const float* vp = P.views + (size_t)(p0 + t * 16 + c) * 3;
                        nb.z = cvt2(vp[0], vp[1]);
                        nb.w = cvt2(vp[2], 0.f);
                    }
                    b0[t] = nb;
                }
            }

            // ---- color L0 : feats -> 64, relu (single-K MFMA, K=32)
            {
                f16x8 wf[4];
#pragma unroll
                for (int b = 0; b < 4; ++b)
                    wf[b] = *(const f16x8*)(lw + OFF_C0 + b * 512 + lane * 8);
#pragma unroll
                for (int t = 0; t < NPT; ++t) {
                    const f16x8 inf = __builtin_bit_cast(f16x8, b0[t]);
                    f32x4 acc[4];
#pragma unroll
                    for (int mt = 0; mt < 4; ++mt) {
                        f32x4 a = (f32x4){0.f, 0.f, 0.f, 0.f};
                        acc[mt] = MFMA(wf[mt], inf, a);
                    }
                    handoff64<true>(acc, b0[t], b1[t]);
                }
            }

            // ---- color L1, L2 : 64 -> 64, relu
            layer64(lw + OFF_C1, lane, b0, b1);
            layer64(lw + OFF_C2, lane, b0, b1);

            // ---- color L3 : 64 -> rgb (features 0..2 at g==0 lanes)
            {
                const f16x8 w0 = *(const f16x8*)(lw + OFF_C3 + 0 * 512 + lane * 8);
                const f16x8 w1 = *(const f16x8*)(lw + OFF_C3 + 1 * 512 + lane * 8);
#pragma unroll
                for (int t = 0; t < NPT; ++t) {
                    f32x4 a = (f32x4){0.f, 0.f, 0.f, 0.f};
                    a = MFMA(w0, __builtin_bit_cast(f16x8, b0[t]), a);
                    a = MFMA(w1, __builtin_bit_cast(f16x8, b1[t]), a);
                    rp[t] = a[0]; gp[t] = a[1]; bp[t] = a[2];
                }
            }

            // ---- branch epilogue: softplus/sigmoid/mask via v_exp/v_log/v_rcp
#pragma unroll
            for (int t = 0; t < NPT; ++t) {
                const float mk = msk[p0 + t * 16 + c];
                const float x  = sig_pre[t];
                const float ex = __expf(x);
                const float sp = (x > 15.f) ? x : 0.69314718f * __log2f(1.f + ex);
                const float sb = sp * mk;
                stot[t] += sb;
                const float sm = sb * mk;
                car[t] += sm * fast_rcp(1.f + __expf(-rp[t]));
                cag[t] += sm * fast_rcp(1.f + __expf(-gp[t]));
                cab[t] += sm * fast_rcp(1.f + __expf(-bp[t]));
            }
        }

        // ---- final blend + store (lanes 0..15 hold the per-point values)
#pragma unroll
        for (int t = 0; t < NPT; ++t) {
            if (lane < 16) {
                const float s   = stot[t] + 1e-9f;
                const float inv = fast_rcp(s);
                float4 o;
                o.x = car[t] * inv; o.y = cag[t] * inv; o.z = cab[t] * inv; o.w = s;
                *(float4*)(P.out + (size_t)(p0 + t * 16 + lane) * 4) = o;
            }
        }
    }
}

extern "C" void kernel_launch(void* const* d_in, const int* in_sizes, int n_in,
                              void* d_out, int out_size, void* d_ws, size_t ws_size,
                              hipStream_t stream) {
    (void)in_sizes; (void)n_in; (void)d_ws; (void)ws_size; (void)out_size;
    Params P;
    P.emb[0] = (const float*)d_in[0];   // embedded_xyz      (bg)
    P.emb[1] = (const float*)d_in[1];   // embedded_xyzt     (fg)
    P.emb[2] = (const float*)d_in[2];   // embedded_xyzt_cam (actor)
    P.views  = (const float*)d_in[3];
    P.mask[0] = (const float*)d_in[4];
    P.mask[1] = (const float*)d_in[5];
    P.mask[2] = (const float*)d_in[6];
    for (int i = 0; i < 21; ++i) P.w[i] = (const float*)d_in[7 + i];
    P.out = (float*)d_out;
    prep_weights<<<108, 256, 0, stream>>>(P);   // 27648 threads, one u32 word each
    nerf_main<<<GRID, BLOCK, 0, stream>>>(P);
}